// Round 17
// baseline (912.980 us; speedup 1.0000x reference)
//
#include <hip/hip_runtime.h>
#include <hip/hip_bf16.h>

#define NTOK 8192
#define NEXP 8
#define DMODEL 1024
#define DHID 4096

typedef __bf16 bf16x8 __attribute__((ext_vector_type(8)));
typedef float f32x4 __attribute__((ext_vector_type(4)));

__device__ __forceinline__ unsigned short f2bf(float f) {
  return __builtin_bit_cast(unsigned short, __float2bfloat16(f));
}

__device__ __forceinline__ void gload_lds16(const void* g, void* l) {
  __builtin_amdgcn_global_load_lds(
      (const __attribute__((address_space(1))) unsigned int*)g,
      (__attribute__((address_space(3))) unsigned int*)l, 16, 0, 0);
}

__device__ __forceinline__ int imin(int a, int b) { return a < b ? a : b; }

// ---------------- workspace layout (bytes) ----------------
constexpr size_t OFF_XB   = 0;                                             // 8192*1024*2
constexpr size_t OFF_W1T  = OFF_XB + (size_t)NTOK * DMODEL * 2;            // [E][H][D] bf16
constexpr size_t OFF_W2T  = OFF_W1T + (size_t)NEXP * DHID * DMODEL * 2;    // [E][D][H] bf16
constexpr size_t OFF_HID  = OFF_W2T + (size_t)NEXP * DMODEL * DHID * 2;    // [16384][4096] bf16
constexpr size_t OFF_IDX  = OFF_HID + (size_t)NTOK * 2 * DHID * 2;         // N*2 int
constexpr size_t OFF_GATE = OFF_IDX + (size_t)NTOK * 2 * 4;                // N*2 float
constexpr size_t OFF_LIST = OFF_GATE + (size_t)NTOK * 2 * 4;               // N*2 int
constexpr size_t OFF_CNT  = OFF_LIST + (size_t)NTOK * 2 * 4;               // 8 int
constexpr size_t OFF_OFFS = OFF_CNT + 128;                                 // 9 int
constexpr size_t OFF_CUR  = OFF_OFFS + 128;                                // 8 int

// ======== merged prep: both weight transposes + gating in ONE dispatch ========
__global__ __launch_bounds__(256) void prep_kernel(
    const float* __restrict__ w1, const float* __restrict__ w2,
    unsigned short* __restrict__ w1t, unsigned short* __restrict__ w2t,
    const float* __restrict__ x, const float* __restrict__ noise,
    const float* __restrict__ Wg_w, const float* __restrict__ Wg_b,
    const float* __restrict__ Wn_w, const float* __restrict__ Wn_b,
    unsigned short* __restrict__ xb, int* __restrict__ topk_idx,
    float* __restrict__ topk_gate, int* __restrict__ counts) {
  __shared__ float sh[64][65];
  const int bid = blockIdx.x;

  if (bid < 16384) {
    const float* in;
    unsigned short* outp;
    int R, C, r0, c0;
    if (bid < 8192) {
      int e = bid >> 10, rem = bid & 1023;
      R = DMODEL; C = DHID;
      in = w1 + (size_t)e * R * C;
      outp = w1t + (size_t)e * R * C;
      r0 = (rem >> 6) * 64;
      c0 = (rem & 63) * 64;
    } else {
      int t = bid - 8192;
      int e = t >> 10, rem = t & 1023;
      R = DHID; C = DMODEL;
      in = w2 + (size_t)e * R * C;
      outp = w2t + (size_t)e * R * C;
      r0 = (rem >> 4) * 64;
      c0 = (rem & 15) * 64;
    }
    int tx = threadIdx.x & 15, ty = threadIdx.x >> 4;
#pragma unroll
    for (int p = 0; p < 4; ++p) {
      int row = ty + p * 16;
      float4 v = *(const float4*)&in[(size_t)(r0 + row) * C + c0 + tx * 4];
      sh[row][tx * 4 + 0] = v.x;
      sh[row][tx * 4 + 1] = v.y;
      sh[row][tx * 4 + 2] = v.z;
      sh[row][tx * 4 + 3] = v.w;
    }
    __syncthreads();
#pragma unroll
    for (int p = 0; p < 4; ++p) {
      int crow = ty + p * 16;
      ushort4 o;
      o.x = f2bf(sh[tx * 4 + 0][crow]);
      o.y = f2bf(sh[tx * 4 + 1][crow]);
      o.z = f2bf(sh[tx * 4 + 2][crow]);
      o.w = f2bf(sh[tx * 4 + 3][crow]);
      *(ushort4*)&outp[(size_t)(c0 + crow) * R + r0 + tx * 4] = o;
    }
    return;
  }

  // ---------------- gating: one wave per token (also emits x bf16) ----------------
  int g = bid - 16384;
  int wave = threadIdx.x >> 6;
  int lane = threadIdx.x & 63;
  int n = g * 4 + wave;
  if (n >= NTOK) return;

  float ag[8] = {0.f, 0.f, 0.f, 0.f, 0.f, 0.f, 0.f, 0.f};
  float an[8] = {0.f, 0.f, 0.f, 0.f, 0.f, 0.f, 0.f, 0.f};
  const float* xr = x + (size_t)n * DMODEL;
  unsigned short* xbr = xb + (size_t)n * DMODEL;
#pragma unroll 4
  for (int i = 0; i < DMODEL / 64; ++i) {
    int d = lane + i * 64;
    float xv = xr[d];
    xbr[d] = f2bf(xv);
    const float4* wg = (const float4*)(Wg_w + (size_t)d * 8);
    const float4* wn = (const float4*)(Wn_w + (size_t)d * 8);
    float4 g0 = wg[0], g1 = wg[1];
    float4 n0 = wn[0], n1 = wn[1];
    ag[0] += xv * g0.x; ag[1] += xv * g0.y; ag[2] += xv * g0.z; ag[3] += xv * g0.w;
    ag[4] += xv * g1.x; ag[5] += xv * g1.y; ag[6] += xv * g1.z; ag[7] += xv * g1.w;
    an[0] += xv * n0.x; an[1] += xv * n0.y; an[2] += xv * n0.z; an[3] += xv * n0.w;
    an[4] += xv * n1.x; an[5] += xv * n1.y; an[6] += xv * n1.z; an[7] += xv * n1.w;
  }
#pragma unroll
  for (int off = 32; off > 0; off >>= 1) {
#pragma unroll
    for (int j = 0; j < 8; ++j) {
      ag[j] += __shfl_down(ag[j], off, 64);
      an[j] += __shfl_down(an[j], off, 64);
    }
  }
  if (lane == 0) {
    float h[8];
#pragma unroll
    for (int e = 0; e < 8; ++e) {
      float gl = ag[e] + Wg_b[e];
      float z = an[e] + Wn_b[e];
      float sp = fmaxf(z, 0.f) + log1pf(expf(-fabsf(z)));  // softplus, stable
      h[e] = gl + noise[(size_t)n * 8 + e] * sp;
    }
    int i0 = 0; float v0 = h[0];
#pragma unroll
    for (int e = 1; e < 8; ++e)
      if (h[e] > v0) { v0 = h[e]; i0 = e; }
    int i1 = -1; float v1 = -1e30f;
#pragma unroll
    for (int e = 0; e < 8; ++e)
      if (e != i0 && h[e] > v1) { v1 = h[e]; i1 = e; }
    float e1 = expf(v1 - v0);
    float inv = 1.f / (1.f + e1);
    topk_idx[n * 2] = i0;
    topk_idx[n * 2 + 1] = i1;
    topk_gate[n * 2] = inv;
    topk_gate[n * 2 + 1] = e1 * inv;
    atomicAdd(&counts[i0], 1);
    atomicAdd(&counts[i1], 1);
  }
}

// ---------------- scan (tiny) ----------------
__global__ void scan_kernel(const int* __restrict__ counts,
                            int* __restrict__ offsets, int* __restrict__ cursor) {
  if (threadIdx.x == 0) {
    int acc = 0;
    for (int e = 0; e < NEXP; ++e) {
      offsets[e] = acc;
      cursor[e] = acc;
      acc += counts[e];
    }
    offsets[NEXP] = acc;
  }
}

// ---------------- scatter tokens into expert lists ----------------
__global__ void scatter_kernel(const int* __restrict__ topk_idx,
                               int* __restrict__ cursor, int* __restrict__ list) {
  int n = blockIdx.x * 256 + threadIdx.x;
  if (n >= NTOK) return;
#pragma unroll
  for (int j = 0; j < 2; ++j) {
    int e = topk_idx[n * 2 + j];
    int pos = atomicAdd(&cursor[e], 1);
    list[pos] = n * 2 + j;
  }
}

// --- grouped expert GEMM: 128x256 tile, BK=32, ring-2 counted-vmcnt, 48 KB ---
// SINGLE VARIABLE vs R12: tile 128x128 -> 128x256 (ring 3 -> 2 to stay at the
// proven-resident 48 KB LDS). Staged bytes/K-step: A 8 KB + B 16 KB = 24 KB
// per 2.1 MFLOP = 87 FLOP/B (+37%); per-GEMM staged 2.1 -> 1.6 GB. R16 proved
// the staging rate (~6.9 TB/s) is CU-side and tier-invariant, so bytes are
// the only dial: predict ~235-245 us per GEMM.
// 4 waves (2m x 2n), per-wave 64x128 output, acc[4][8] = 128 VGPR.
// Per K-step: VMW(6) [tile t's 6 loads landed; t+1's 6 in flight] -> barrier
// -> 12 ds_read_b128 + 32 MFMA -> lgkm(0) -> barrier -> stage t+2 into freed
// slot. Swizzle both sides (2-way = free): chunk c^((row>>1)&3), read
// kg^((lr>>1)&3). XCD map = R12: e = lin&7, by (m) fastest.
#define VMW(N) asm volatile("s_waitcnt vmcnt(" #N ")" ::: "memory")

template <int MODE>
__global__ __launch_bounds__(256, 2) void expert_gemm(
    const unsigned short* __restrict__ Asrc, const unsigned short* __restrict__ Bt,
    const float* __restrict__ bias, const int* __restrict__ offsets,
    const int* __restrict__ list, const float* __restrict__ gates,
    unsigned short* __restrict__ hid, float* __restrict__ out) {
  constexpr int Krow = MODE ? DHID : DMODEL;   // row stride of A and B
  constexpr int Nout = MODE ? DMODEL : DHID;
  constexpr int NT = Krow / 32;                // fc1: 32, fc2: 128

  const int gx = gridDim.x;
  const int lin = blockIdx.x + gx * (blockIdx.y + 64 * blockIdx.z);
  const int e = lin & 7;                       // expert == XCD (lin % 8)
  const int r = lin >> 3;
  const int by = r & 63;                       // m fastest
  const int bx = r >> 6;

  const int off = offsets[e];
  const int ne = offsets[e + 1] - off;
  const int m0 = by * 128;
  if (m0 >= ne) return;
  const int n0 = bx * 256;

  __shared__ alignas(16) unsigned short Al[2][128 * 32];
  __shared__ alignas(16) unsigned short Bl[2][256 * 32];

  const int tid = threadIdx.x;
  const int lane = tid & 63;
  const int w = tid >> 6;
  const int wm = (w >> 1) * 64;                // wave rows: 0 / 64
  const int wn = (w & 1) * 128;                // wave cols: 0 / 128
  const int lr = lane & 15;
  const int kg = lane >> 4;
  const int chrd = (kg ^ ((lr >> 1) & 3)) * 8; // swizzled ds_read chunk (ushorts)

  // staging: A = 2 chunks/thread (128 rows x 4 chunks), B = 4 chunks/thread
  const unsigned short* srcA[2];
  const unsigned short* srcB[4];
#pragma unroll
  for (int i = 0; i < 2; ++i) {
    int q = tid + i * 256;           // row = q>>2 (0..127), c = q&3
    int rr = q >> 2, c = q & 3;
    int cs = c ^ ((rr >> 1) & 3);
    int p = off + imin(m0 + rr, ne - 1);
    if (MODE == 0) {
      int token = list[p] >> 1;
      srcA[i] = Asrc + (size_t)token * DMODEL + cs * 8;
    } else {
      srcA[i] = Asrc + (size_t)p * DHID + cs * 8;
    }
  }
#pragma unroll
  for (int i = 0; i < 4; ++i) {
    int q = tid + i * 256;           // row = q>>2 (0..255), c = q&3
    int rr = q >> 2, c = q & 3;
    int cs = c ^ ((rr >> 1) & 3);
    srcB[i] = Bt + (size_t)e * Nout * Krow + (size_t)(n0 + rr) * Krow + cs * 8;
  }

  f32x4 acc[4][8] = {};

  auto stage = [&](int slot, int kt) {
#pragma unroll
    for (int i = 0; i < 2; ++i)
      gload_lds16(srcA[i] + kt * 32, &Al[slot][(tid + i * 256) * 8]);
#pragma unroll
    for (int i = 0; i < 4; ++i)
      gload_lds16(srcB[i] + kt * 32, &Bl[slot][(tid + i * 256) * 8]);
  };

  auto compute = [&](int slot) {
    bf16x8 af[4], bfr[8];
#pragma unroll
    for (int mf = 0; mf < 4; ++mf)
      af[mf] = *(const bf16x8*)&Al[slot][(wm + mf * 16 + lr) * 32 + chrd];
#pragma unroll
    for (int nf = 0; nf < 8; ++nf)
      bfr[nf] = *(const bf16x8*)&Bl[slot][(wn + nf * 16 + lr) * 32 + chrd];
    asm volatile("s_waitcnt lgkmcnt(0)" ::: "memory");
    __builtin_amdgcn_sched_barrier(0);
#pragma unroll
    for (int mf = 0; mf < 4; ++mf)
#pragma unroll
      for (int nf = 0; nf < 8; ++nf)
        acc[mf][nf] = __builtin_amdgcn_mfma_f32_16x16x32_bf16(af[mf], bfr[nf],
                                                              acc[mf][nf], 0, 0, 0);
  };

  // prologue: fill the 2-slot ring (12 loads/thread outstanding)
  stage(0, 0);
  stage(1, 1);

  int cur = 0;
  for (int t = 0; t < NT; ++t) {
    if (t < NT - 1) { VMW(6); }        // tile t landed; t+1's 6 in flight
    else { VMW(0); }
    __builtin_amdgcn_s_barrier();      // tile t fully in LDS for all waves
    __builtin_amdgcn_sched_barrier(0);
    compute(cur);
    asm volatile("s_waitcnt lgkmcnt(0)" ::: "memory");
    __builtin_amdgcn_sched_barrier(0);
    __builtin_amdgcn_s_barrier();      // all waves done reading slot cur
    if (t + 2 < NT) stage(cur, t + 2); // overwrite freed slot
    cur ^= 1;
  }

  // epilogue: C frag (16x16): col = lane&15, row = (lane>>4)*4 + j
  if (MODE == 0) {
#pragma unroll
    for (int mf = 0; mf < 4; ++mf) {
#pragma unroll
      for (int j = 0; j < 4; ++j) {
        int rloc = wm + mf * 16 + kg * 4 + j;
        int row = m0 + rloc;
        if (row < ne) {
          size_t p = (size_t)(off + row);
#pragma unroll
          for (int nf = 0; nf < 8; ++nf) {
            int col = n0 + wn + nf * 16 + lr;
            float v = acc[mf][nf][j] + bias[(size_t)e * Nout + col];
            hid[p * DHID + col] = f2bf(fmaxf(v, 0.f));
          }
        }
      }
    }
  } else {
#pragma unroll
    for (int mf = 0; mf < 4; ++mf) {
#pragma unroll
      for (int j = 0; j < 4; ++j) {
        int rloc = wm + mf * 16 + kg * 4 + j;
        int row = m0 + rloc;
        if (row < ne) {
          int lv = list[off + row];
          int token = lv >> 1;
          float g = gates[lv];
#pragma unroll
          for (int nf = 0; nf < 8; ++nf) {
            int col = n0 + wn + nf * 16 + lr;
            float v = (acc[mf][nf][j] + bias[(size_t)e * Nout + col]) * g;
            atomicAdd(&out[(size_t)token * DMODEL + col], v);
          }
        }
      }
    }
  }
}

extern "C" void kernel_launch(void* const* d_in, const int* in_sizes, int n_in,
                              void* d_out, int out_size, void* d_ws, size_t ws_size,
                              hipStream_t stream) {
  const float* x = (const float*)d_in[0];
  const float* noise = (const float*)d_in[1];
  const float* Wg_w = (const float*)d_in[2];
  const float* Wg_b = (const float*)d_in[3];
  const float* Wn_w = (const float*)d_in[4];
  const float* Wn_b = (const float*)d_in[5];
  const float* w1 = (const float*)d_in[6];
  const float* b1 = (const float*)d_in[7];
  const float* w2 = (const float*)d_in[8];
  const float* b2 = (const float*)d_in[9];
  float* out = (float*)d_out;

  char* ws = (char*)d_ws;
  unsigned short* xb = (unsigned short*)(ws + OFF_XB);
  unsigned short* w1t = (unsigned short*)(ws + OFF_W1T);
  unsigned short* w2t = (unsigned short*)(ws + OFF_W2T);
  unsigned short* hid = (unsigned short*)(ws + OFF_HID);
  int* topk_idx = (int*)(ws + OFF_IDX);
  float* topk_gate = (float*)(ws + OFF_GATE);
  int* list = (int*)(ws + OFF_LIST);
  int* counts = (int*)(ws + OFF_CNT);
  int* offsets = (int*)(ws + OFF_OFFS);
  int* cursor = (int*)(ws + OFF_CUR);

  hipMemsetAsync(out, 0, (size_t)NTOK * DMODEL * sizeof(float), stream);
  hipMemsetAsync(counts, 0, NEXP * sizeof(int), stream);

  // merged transposes + gating: 16384 transpose tiles + 2048 gating blocks
  prep_kernel<<<18432, 256, 0, stream>>>(w1, w2, w1t, w2t, x, noise, Wg_w, Wg_b,
                                         Wn_w, Wn_b, xb, topk_idx, topk_gate,
                                         counts);
  scan_kernel<<<1, 64, 0, stream>>>(counts, offsets, cursor);
  scatter_kernel<<<NTOK / 256, 256, 0, stream>>>(topk_idx, cursor, list);

  // fc1: per expert [ne x 4096] = A[ne x 1024] * B[1024 x 4096], 16 n-panels
  expert_gemm<0><<<dim3(16, 64, NEXP), 256, 0, stream>>>(
      xb, w1t, b1, offsets, list, topk_gate, hid, nullptr);
  // fc2: out += gate * (hid[ne x 4096] * B[4096 x 1024]), 4 n-panels
  expert_gemm<1><<<dim3(4, 64, NEXP), 256, 0, stream>>>(
      hid, w2t, b2, offsets, list, topk_gate, nullptr, out);
}

// Round 18
// 827.092 us; speedup vs baseline: 1.1038x; 1.1038x over previous
//
#include <hip/hip_runtime.h>
#include <hip/hip_bf16.h>

#define NTOK 8192
#define NEXP 8
#define DMODEL 1024
#define DHID 4096

typedef __bf16 bf16x8 __attribute__((ext_vector_type(8)));
typedef float f32x4 __attribute__((ext_vector_type(4)));

__device__ __forceinline__ unsigned short f2bf(float f) {
  return __builtin_bit_cast(unsigned short, __float2bfloat16(f));
}

__device__ __forceinline__ void gload_lds16(const void* g, void* l) {
  __builtin_amdgcn_global_load_lds(
      (const __attribute__((address_space(1))) unsigned int*)g,
      (__attribute__((address_space(3))) unsigned int*)l, 16, 0, 0);
}

__device__ __forceinline__ int imin(int a, int b) { return a < b ? a : b; }

// ---------------- workspace layout (bytes) ----------------
constexpr size_t OFF_XB   = 0;                                             // 8192*1024*2
constexpr size_t OFF_W1T  = OFF_XB + (size_t)NTOK * DMODEL * 2;            // [E][H][D] bf16
constexpr size_t OFF_W2T  = OFF_W1T + (size_t)NEXP * DHID * DMODEL * 2;    // [E][D][H] bf16
constexpr size_t OFF_HID  = OFF_W2T + (size_t)NEXP * DMODEL * DHID * 2;    // [16384][4096] bf16
constexpr size_t OFF_IDX  = OFF_HID + (size_t)NTOK * 2 * DHID * 2;         // N*2 int
constexpr size_t OFF_GATE = OFF_IDX + (size_t)NTOK * 2 * 4;                // N*2 float
constexpr size_t OFF_LIST = OFF_GATE + (size_t)NTOK * 2 * 4;               // N*2 int
constexpr size_t OFF_CNT  = OFF_LIST + (size_t)NTOK * 2 * 4;               // 8 int
constexpr size_t OFF_OFFS = OFF_CNT + 128;                                 // 9 int
constexpr size_t OFF_CUR  = OFF_OFFS + 128;                                // 8 int

// ======== merged prep: both weight transposes + gating in ONE dispatch ========
__global__ __launch_bounds__(256) void prep_kernel(
    const float* __restrict__ w1, const float* __restrict__ w2,
    unsigned short* __restrict__ w1t, unsigned short* __restrict__ w2t,
    const float* __restrict__ x, const float* __restrict__ noise,
    const float* __restrict__ Wg_w, const float* __restrict__ Wg_b,
    const float* __restrict__ Wn_w, const float* __restrict__ Wn_b,
    unsigned short* __restrict__ xb, int* __restrict__ topk_idx,
    float* __restrict__ topk_gate, int* __restrict__ counts) {
  __shared__ float sh[64][65];
  const int bid = blockIdx.x;

  if (bid < 16384) {
    const float* in;
    unsigned short* outp;
    int R, C, r0, c0;
    if (bid < 8192) {
      int e = bid >> 10, rem = bid & 1023;
      R = DMODEL; C = DHID;
      in = w1 + (size_t)e * R * C;
      outp = w1t + (size_t)e * R * C;
      r0 = (rem >> 6) * 64;
      c0 = (rem & 63) * 64;
    } else {
      int t = bid - 8192;
      int e = t >> 10, rem = t & 1023;
      R = DHID; C = DMODEL;
      in = w2 + (size_t)e * R * C;
      outp = w2t + (size_t)e * R * C;
      r0 = (rem >> 4) * 64;
      c0 = (rem & 15) * 64;
    }
    int tx = threadIdx.x & 15, ty = threadIdx.x >> 4;
#pragma unroll
    for (int p = 0; p < 4; ++p) {
      int row = ty + p * 16;
      float4 v = *(const float4*)&in[(size_t)(r0 + row) * C + c0 + tx * 4];
      sh[row][tx * 4 + 0] = v.x;
      sh[row][tx * 4 + 1] = v.y;
      sh[row][tx * 4 + 2] = v.z;
      sh[row][tx * 4 + 3] = v.w;
    }
    __syncthreads();
#pragma unroll
    for (int p = 0; p < 4; ++p) {
      int crow = ty + p * 16;
      ushort4 o;
      o.x = f2bf(sh[tx * 4 + 0][crow]);
      o.y = f2bf(sh[tx * 4 + 1][crow]);
      o.z = f2bf(sh[tx * 4 + 2][crow]);
      o.w = f2bf(sh[tx * 4 + 3][crow]);
      *(ushort4*)&outp[(size_t)(c0 + crow) * R + r0 + tx * 4] = o;
    }
    return;
  }

  // ---------------- gating: one wave per token (also emits x bf16) ----------------
  int g = bid - 16384;
  int wave = threadIdx.x >> 6;
  int lane = threadIdx.x & 63;
  int n = g * 4 + wave;
  if (n >= NTOK) return;

  float ag[8] = {0.f, 0.f, 0.f, 0.f, 0.f, 0.f, 0.f, 0.f};
  float an[8] = {0.f, 0.f, 0.f, 0.f, 0.f, 0.f, 0.f, 0.f};
  const float* xr = x + (size_t)n * DMODEL;
  unsigned short* xbr = xb + (size_t)n * DMODEL;
#pragma unroll 4
  for (int i = 0; i < DMODEL / 64; ++i) {
    int d = lane + i * 64;
    float xv = xr[d];
    xbr[d] = f2bf(xv);
    const float4* wg = (const float4*)(Wg_w + (size_t)d * 8);
    const float4* wn = (const float4*)(Wn_w + (size_t)d * 8);
    float4 g0 = wg[0], g1 = wg[1];
    float4 n0 = wn[0], n1 = wn[1];
    ag[0] += xv * g0.x; ag[1] += xv * g0.y; ag[2] += xv * g0.z; ag[3] += xv * g0.w;
    ag[4] += xv * g1.x; ag[5] += xv * g1.y; ag[6] += xv * g1.z; ag[7] += xv * g1.w;
    an[0] += xv * n0.x; an[1] += xv * n0.y; an[2] += xv * n0.z; an[3] += xv * n0.w;
    an[4] += xv * n1.x; an[5] += xv * n1.y; an[6] += xv * n1.z; an[7] += xv * n1.w;
  }
#pragma unroll
  for (int off = 32; off > 0; off >>= 1) {
#pragma unroll
    for (int j = 0; j < 8; ++j) {
      ag[j] += __shfl_down(ag[j], off, 64);
      an[j] += __shfl_down(an[j], off, 64);
    }
  }
  if (lane == 0) {
    float h[8];
#pragma unroll
    for (int e = 0; e < 8; ++e) {
      float gl = ag[e] + Wg_b[e];
      float z = an[e] + Wn_b[e];
      float sp = fmaxf(z, 0.f) + log1pf(expf(-fabsf(z)));  // softplus, stable
      h[e] = gl + noise[(size_t)n * 8 + e] * sp;
    }
    int i0 = 0; float v0 = h[0];
#pragma unroll
    for (int e = 1; e < 8; ++e)
      if (h[e] > v0) { v0 = h[e]; i0 = e; }
    int i1 = -1; float v1 = -1e30f;
#pragma unroll
    for (int e = 0; e < 8; ++e)
      if (e != i0 && h[e] > v1) { v1 = h[e]; i1 = e; }
    float e1 = expf(v1 - v0);
    float inv = 1.f / (1.f + e1);
    topk_idx[n * 2] = i0;
    topk_idx[n * 2 + 1] = i1;
    topk_gate[n * 2] = inv;
    topk_gate[n * 2 + 1] = e1 * inv;
    atomicAdd(&counts[i0], 1);
    atomicAdd(&counts[i1], 1);
  }
}

// ---------------- scan (tiny) ----------------
__global__ void scan_kernel(const int* __restrict__ counts,
                            int* __restrict__ offsets, int* __restrict__ cursor) {
  if (threadIdx.x == 0) {
    int acc = 0;
    for (int e = 0; e < NEXP; ++e) {
      offsets[e] = acc;
      cursor[e] = acc;
      acc += counts[e];
    }
    offsets[NEXP] = acc;
  }
}

// ---------------- scatter tokens into expert lists ----------------
__global__ void scatter_kernel(const int* __restrict__ topk_idx,
                               int* __restrict__ cursor, int* __restrict__ list) {
  int n = blockIdx.x * 256 + threadIdx.x;
  if (n >= NTOK) return;
#pragma unroll
  for (int j = 0; j < 2; ++j) {
    int e = topk_idx[n * 2 + j];
    int pos = atomicAdd(&cursor[e], 1);
    list[pos] = n * 2 + j;
  }
}

// ------- grouped expert GEMM: 128x128, BK=32, depth-3 counted-vmcnt ring -------
// The session's measured optimum (R12 = 829 us total; GEMMs 307/308). 4 waves
// (2x2), 64x64/wave; LDS 3-slot ring 48 KB (the largest footprint that holds
// 2 blocks/CU). Per K-step: VMW(8) [tile t retired; t+1,t+2's 8 loads in
// flight across both barriers] -> barrier -> 8 ds_read_b128 + 16 MFMA ->
// lgkm(0) -> barrier -> stage t+3 into freed slot.
// Swizzle both sides (2-way = free): chunk c^((row>>1)&3) / kg^((lr>>1)&3).
// fc1 (MODE 0): XCD-pinned expert + 8x8 L2 supertiles, serpentine.
// fc2 (MODE 1): full-K, by fastest. (fc2 setprio removed -- measured null.)
//
// Session model (R1-R17): time = staged-bytes / ~6.9 TB/s at the ~8 waves/CU
// residency ceiling; rate is source-tier-invariant (R16) and schedule-
// invariant; residency immovable from source (VGPR 64-128, LDS 16-72 KB).
#define VMW(N) asm volatile("s_waitcnt vmcnt(" #N ")" ::: "memory")

template <int MODE>
__global__ __launch_bounds__(256, 4) void expert_gemm(
    const unsigned short* __restrict__ Asrc, const unsigned short* __restrict__ Bt,
    const float* __restrict__ bias, const int* __restrict__ offsets,
    const int* __restrict__ list, const float* __restrict__ gates,
    unsigned short* __restrict__ hid, float* __restrict__ out) {
  constexpr int Krow = MODE ? DHID : DMODEL;   // row stride of A and B
  constexpr int Nout = MODE ? DMODEL : DHID;
  constexpr int NT = Krow / 32;                // fc1: 32, fc2: 128

  const int gx = gridDim.x, gy = gridDim.y;
  const int lin = blockIdx.x + gx * (blockIdx.y + gy * blockIdx.z);
  const int e = lin & 7;                       // expert == XCD (lin % 8)
  int r = lin >> 3;

  int by, bx;
  if (MODE == 0) {
    int st = r >> 6;                           // supertile 0..31
    int inner = r & 63;
    int sm = st >> 2, sn = st & 3;
    if (sm & 1) sn = 3 - sn;                   // serpentine: A-super stays hot
    by = sm * 8 + (inner >> 3);                // 0..63
    bx = sn * 8 + (inner & 7);                 // 0..31
  } else {
    by = r & 63;
    bx = r >> 6;                               // 0..7
  }

  const int off = offsets[e];
  const int ne = offsets[e + 1] - off;
  const int m0 = by * 128;
  if (m0 >= ne) return;
  const int n0 = bx * 128;

  __shared__ alignas(16) unsigned short Al[3][128 * 32];
  __shared__ alignas(16) unsigned short Bl[3][128 * 32];

  const int tid = threadIdx.x;
  const int lane = tid & 63;
  const int w = tid >> 6;
  const int wm = (w >> 1) * 64;
  const int wn = (w & 1) * 64;
  const int lr = lane & 15;
  const int kg = lane >> 4;
  const int chrd = (kg ^ ((lr >> 1) & 3)) * 8;  // swizzled ds_read chunk (ushorts)

  // per-thread staging sources (2 x 16B chunks each for A and B per K-tile)
  const unsigned short* srcA[2];
  const unsigned short* srcB[2];
#pragma unroll
  for (int i = 0; i < 2; ++i) {
    int q = tid + i * 256;           // chunk-linear in 128x32 tile (4 chunks/row)
    int rr = q >> 2, c = q & 3;
    int cs = c ^ ((rr >> 1) & 3);    // inverse-swizzled source chunk
    int p = off + imin(m0 + rr, ne - 1);
    if (MODE == 0) {
      int token = list[p] >> 1;
      srcA[i] = Asrc + (size_t)token * DMODEL + cs * 8;
    } else {
      srcA[i] = Asrc + (size_t)p * DHID + cs * 8;
    }
    srcB[i] = Bt + (size_t)e * Nout * Krow + (size_t)(n0 + rr) * Krow + cs * 8;
  }

  f32x4 acc[4][4] = {};

  auto stage = [&](int slot, int kt) {
#pragma unroll
    for (int i = 0; i < 2; ++i) {
      int q = tid + i * 256;
      gload_lds16(srcA[i] + kt * 32, &Al[slot][q * 8]);
      gload_lds16(srcB[i] + kt * 32, &Bl[slot][q * 8]);
    }
  };

  auto compute = [&](int slot) {
    bf16x8 af[4], bfr[4];
#pragma unroll
    for (int mf = 0; mf < 4; ++mf)
      af[mf] = *(const bf16x8*)&Al[slot][(wm + mf * 16 + lr) * 32 + chrd];
#pragma unroll
    for (int nf = 0; nf < 4; ++nf)
      bfr[nf] = *(const bf16x8*)&Bl[slot][(wn + nf * 16 + lr) * 32 + chrd];
    asm volatile("s_waitcnt lgkmcnt(0)" ::: "memory");
    __builtin_amdgcn_sched_barrier(0);
#pragma unroll
    for (int mf = 0; mf < 4; ++mf)
#pragma unroll
      for (int nf = 0; nf < 4; ++nf)
        acc[mf][nf] = __builtin_amdgcn_mfma_f32_16x16x32_bf16(af[mf], bfr[nf],
                                                              acc[mf][nf], 0, 0, 0);
  };

  // prologue: fill the 3-slot ring (12 loads/thread outstanding)
  stage(0, 0);
  stage(1, 1);
  stage(2, 2);

  int cur = 0;
  for (int t = 0; t < NT; ++t) {
    if (t < NT - 2) { VMW(8); }        // tile t retired; t+1,t+2 in flight
    else if (t == NT - 2) { VMW(4); }
    else { VMW(0); }
    __builtin_amdgcn_s_barrier();      // tile t fully in LDS for all waves
    __builtin_amdgcn_sched_barrier(0);
    compute(cur);
    asm volatile("s_waitcnt lgkmcnt(0)" ::: "memory");
    __builtin_amdgcn_sched_barrier(0);
    __builtin_amdgcn_s_barrier();      // all waves done reading slot cur
    if (t + 3 < NT) stage(cur, t + 3); // overwrite freed slot, 2 steps ahead
    cur = (cur == 2) ? 0 : cur + 1;
  }

  // epilogue: C frag (16x16): col = lane&15, row = (lane>>4)*4 + j
  if (MODE == 0) {
#pragma unroll
    for (int mf = 0; mf < 4; ++mf) {
#pragma unroll
      for (int j = 0; j < 4; ++j) {
        int rloc = wm + mf * 16 + kg * 4 + j;
        int row = m0 + rloc;
        if (row < ne) {
          size_t p = (size_t)(off + row);
#pragma unroll
          for (int nf = 0; nf < 4; ++nf) {
            int col = n0 + wn + nf * 16 + lr;
            float v = acc[mf][nf][j] + bias[(size_t)e * Nout + col];
            hid[p * DHID + col] = f2bf(fmaxf(v, 0.f));
          }
        }
      }
    }
  } else {
#pragma unroll
    for (int mf = 0; mf < 4; ++mf) {
#pragma unroll
      for (int j = 0; j < 4; ++j) {
        int rloc = wm + mf * 16 + kg * 4 + j;
        int row = m0 + rloc;
        if (row < ne) {
          int lv = list[off + row];
          int token = lv >> 1;
          float g = gates[lv];
#pragma unroll
          for (int nf = 0; nf < 4; ++nf) {
            int col = n0 + wn + nf * 16 + lr;
            float v = (acc[mf][nf][j] + bias[(size_t)e * Nout + col]) * g;
            atomicAdd(&out[(size_t)token * DMODEL + col], v);
          }
        }
      }
    }
  }
}

extern "C" void kernel_launch(void* const* d_in, const int* in_sizes, int n_in,
                              void* d_out, int out_size, void* d_ws, size_t ws_size,
                              hipStream_t stream) {
  const float* x = (const float*)d_in[0];
  const float* noise = (const float*)d_in[1];
  const float* Wg_w = (const float*)d_in[2];
  const float* Wg_b = (const float*)d_in[3];
  const float* Wn_w = (const float*)d_in[4];
  const float* Wn_b = (const float*)d_in[5];
  const float* w1 = (const float*)d_in[6];
  const float* b1 = (const float*)d_in[7];
  const float* w2 = (const float*)d_in[8];
  const float* b2 = (const float*)d_in[9];
  float* out = (float*)d_out;

  char* ws = (char*)d_ws;
  unsigned short* xb = (unsigned short*)(ws + OFF_XB);
  unsigned short* w1t = (unsigned short*)(ws + OFF_W1T);
  unsigned short* w2t = (unsigned short*)(ws + OFF_W2T);
  unsigned short* hid = (unsigned short*)(ws + OFF_HID);
  int* topk_idx = (int*)(ws + OFF_IDX);
  float* topk_gate = (float*)(ws + OFF_GATE);
  int* list = (int*)(ws + OFF_LIST);
  int* counts = (int*)(ws + OFF_CNT);
  int* offsets = (int*)(ws + OFF_OFFS);
  int* cursor = (int*)(ws + OFF_CUR);

  hipMemsetAsync(out, 0, (size_t)NTOK * DMODEL * sizeof(float), stream);
  hipMemsetAsync(counts, 0, NEXP * sizeof(int), stream);

  // merged transposes + gating: 16384 transpose tiles + 2048 gating blocks
  prep_kernel<<<18432, 256, 0, stream>>>(w1, w2, w1t, w2t, x, noise, Wg_w, Wg_b,
                                         Wn_w, Wn_b, xb, topk_idx, topk_gate,
                                         counts);
  scan_kernel<<<1, 64, 0, stream>>>(counts, offsets, cursor);
  scatter_kernel<<<NTOK / 256, 256, 0, stream>>>(topk_idx, cursor, list);

  // fc1: per expert [ne x 4096] = A[ne x 1024] * B[1024 x 4096]
  expert_gemm<0><<<dim3(32, 64, NEXP), 256, 0, stream>>>(
      xb, w1t, b1, offsets, list, topk_gate, hid, nullptr);
  // fc2: out += gate * (hid[ne x 4096] * B[4096 x 1024])
  expert_gemm<1><<<dim3(8, 64, NEXP), 256, 0, stream>>>(
      hid, w2t, b2, offsets, list, topk_gate, nullptr, out);
}

// Round 19
// 812.742 us; speedup vs baseline: 1.1233x; 1.0177x over previous
//
#include <hip/hip_runtime.h>
#include <hip/hip_bf16.h>

#define NTOK 8192
#define NEXP 8
#define DMODEL 1024
#define DHID 4096

typedef __bf16 bf16x8 __attribute__((ext_vector_type(8)));
typedef float f32x4 __attribute__((ext_vector_type(4)));

__device__ __forceinline__ unsigned short f2bf(float f) {
  return __builtin_bit_cast(unsigned short, __float2bfloat16(f));
}

__device__ __forceinline__ void gload_lds16(const void* g, void* l) {
  __builtin_amdgcn_global_load_lds(
      (const __attribute__((address_space(1))) unsigned int*)g,
      (__attribute__((address_space(3))) unsigned int*)l, 16, 0, 0);
}

__device__ __forceinline__ int imin(int a, int b) { return a < b ? a : b; }

// ---------------- workspace layout (bytes) ----------------
constexpr size_t OFF_XB   = 0;                                             // 8192*1024*2
constexpr size_t OFF_W1T  = OFF_XB + (size_t)NTOK * DMODEL * 2;            // [E][H][D] bf16
constexpr size_t OFF_W2T  = OFF_W1T + (size_t)NEXP * DHID * DMODEL * 2;    // [E][D][H] bf16
constexpr size_t OFF_HID  = OFF_W2T + (size_t)NEXP * DMODEL * DHID * 2;    // [16384][4096] bf16
constexpr size_t OFF_IDX  = OFF_HID + (size_t)NTOK * 2 * DHID * 2;         // N*2 int
constexpr size_t OFF_GATE = OFF_IDX + (size_t)NTOK * 2 * 4;                // N*2 float
constexpr size_t OFF_LIST = OFF_GATE + (size_t)NTOK * 2 * 4;               // N*2 int
constexpr size_t OFF_CNT  = OFF_LIST + (size_t)NTOK * 2 * 4;               // 8 int
constexpr size_t OFF_OFFS = OFF_CNT + 128;                                 // 9 int
constexpr size_t OFF_CUR  = OFF_OFFS + 128;                                // 8 int

// ======== prep: w1 transpose + gating (w2 transpose moved into fc1's grid) ====
// blocks [0,8192):    w1 [E][1024][4096] f32 -> w1t [E][4096][1024] bf16
// blocks [8192,10240): gating, 4 tokens/block
__global__ __launch_bounds__(256) void prep_kernel(
    const float* __restrict__ w1, unsigned short* __restrict__ w1t,
    const float* __restrict__ x, const float* __restrict__ noise,
    const float* __restrict__ Wg_w, const float* __restrict__ Wg_b,
    const float* __restrict__ Wn_w, const float* __restrict__ Wn_b,
    unsigned short* __restrict__ xb, int* __restrict__ topk_idx,
    float* __restrict__ topk_gate, int* __restrict__ counts) {
  __shared__ float sh[64][65];
  const int bid = blockIdx.x;

  if (bid < 8192) {
    int e = bid >> 10, rem = bid & 1023;
    const int R = DMODEL, C = DHID;
    const float* in = w1 + (size_t)e * R * C;
    unsigned short* outp = w1t + (size_t)e * R * C;
    int r0 = (rem >> 6) * 64;
    int c0 = (rem & 63) * 64;
    int tx = threadIdx.x & 15, ty = threadIdx.x >> 4;
#pragma unroll
    for (int p = 0; p < 4; ++p) {
      int row = ty + p * 16;
      float4 v = *(const float4*)&in[(size_t)(r0 + row) * C + c0 + tx * 4];
      sh[row][tx * 4 + 0] = v.x;
      sh[row][tx * 4 + 1] = v.y;
      sh[row][tx * 4 + 2] = v.z;
      sh[row][tx * 4 + 3] = v.w;
    }
    __syncthreads();
#pragma unroll
    for (int p = 0; p < 4; ++p) {
      int crow = ty + p * 16;
      ushort4 o;
      o.x = f2bf(sh[tx * 4 + 0][crow]);
      o.y = f2bf(sh[tx * 4 + 1][crow]);
      o.z = f2bf(sh[tx * 4 + 2][crow]);
      o.w = f2bf(sh[tx * 4 + 3][crow]);
      *(ushort4*)&outp[(size_t)(c0 + crow) * R + r0 + tx * 4] = o;
    }
    return;
  }

  // ---------------- gating: one wave per token (also emits x bf16) ----------------
  int g = bid - 8192;
  int wave = threadIdx.x >> 6;
  int lane = threadIdx.x & 63;
  int n = g * 4 + wave;
  if (n >= NTOK) return;

  float ag[8] = {0.f, 0.f, 0.f, 0.f, 0.f, 0.f, 0.f, 0.f};
  float an[8] = {0.f, 0.f, 0.f, 0.f, 0.f, 0.f, 0.f, 0.f};
  const float* xr = x + (size_t)n * DMODEL;
  unsigned short* xbr = xb + (size_t)n * DMODEL;
#pragma unroll 4
  for (int i = 0; i < DMODEL / 64; ++i) {
    int d = lane + i * 64;
    float xv = xr[d];
    xbr[d] = f2bf(xv);
    const float4* wg = (const float4*)(Wg_w + (size_t)d * 8);
    const float4* wn = (const float4*)(Wn_w + (size_t)d * 8);
    float4 g0 = wg[0], g1 = wg[1];
    float4 n0 = wn[0], n1 = wn[1];
    ag[0] += xv * g0.x; ag[1] += xv * g0.y; ag[2] += xv * g0.z; ag[3] += xv * g0.w;
    ag[4] += xv * g1.x; ag[5] += xv * g1.y; ag[6] += xv * g1.z; ag[7] += xv * g1.w;
    an[0] += xv * n0.x; an[1] += xv * n0.y; an[2] += xv * n0.z; an[3] += xv * n0.w;
    an[4] += xv * n1.x; an[5] += xv * n1.y; an[6] += xv * n1.z; an[7] += xv * n1.w;
  }
#pragma unroll
  for (int off = 32; off > 0; off >>= 1) {
#pragma unroll
    for (int j = 0; j < 8; ++j) {
      ag[j] += __shfl_down(ag[j], off, 64);
      an[j] += __shfl_down(an[j], off, 64);
    }
  }
  if (lane == 0) {
    float h[8];
#pragma unroll
    for (int e = 0; e < 8; ++e) {
      float gl = ag[e] + Wg_b[e];
      float z = an[e] + Wn_b[e];
      float sp = fmaxf(z, 0.f) + log1pf(expf(-fabsf(z)));  // softplus, stable
      h[e] = gl + noise[(size_t)n * 8 + e] * sp;
    }
    int i0 = 0; float v0 = h[0];
#pragma unroll
    for (int e = 1; e < 8; ++e)
      if (h[e] > v0) { v0 = h[e]; i0 = e; }
    int i1 = -1; float v1 = -1e30f;
#pragma unroll
    for (int e = 0; e < 8; ++e)
      if (e != i0 && h[e] > v1) { v1 = h[e]; i1 = e; }
    float e1 = expf(v1 - v0);
    float inv = 1.f / (1.f + e1);
    topk_idx[n * 2] = i0;
    topk_idx[n * 2 + 1] = i1;
    topk_gate[n * 2] = inv;
    topk_gate[n * 2 + 1] = e1 * inv;
    atomicAdd(&counts[i0], 1);
    atomicAdd(&counts[i1], 1);
  }
}

// ---------------- scan (tiny) ----------------
__global__ void scan_kernel(const int* __restrict__ counts,
                            int* __restrict__ offsets, int* __restrict__ cursor) {
  if (threadIdx.x == 0) {
    int acc = 0;
    for (int e = 0; e < NEXP; ++e) {
      offsets[e] = acc;
      cursor[e] = acc;
      acc += counts[e];
    }
    offsets[NEXP] = acc;
  }
}

// ---------------- scatter tokens into expert lists ----------------
__global__ void scatter_kernel(const int* __restrict__ topk_idx,
                               int* __restrict__ cursor, int* __restrict__ list) {
  int n = blockIdx.x * 256 + threadIdx.x;
  if (n >= NTOK) return;
#pragma unroll
  for (int j = 0; j < 2; ++j) {
    int e = topk_idx[n * 2 + j];
    int pos = atomicAdd(&cursor[e], 1);
    list[pos] = n * 2 + j;
  }
}

// ------- grouped expert GEMM: 128x128, BK=32, depth-3 counted-vmcnt ring -------
// R12/R18 measured-optimum body. MODE 0 additionally carries the w2 transpose
// as appended blocks [16384, 24576): they backfill CUs as fc1's GEMM blocks
// retire, overlapping the ~134 MB fp32 HBM read with fc1's staging-bound
// compute (HBM is ~90% idle during the GEMM). LDS for the transpose scratch
// ALIASES the GEMM ring (16.6 KB inside Al's 24 KB) -- static LDS stays 48 KB
// so the 2-blocks/CU residency is preserved.
#define VMW(N) asm volatile("s_waitcnt vmcnt(" #N ")" ::: "memory")

template <int MODE>
__global__ __launch_bounds__(256, 4) void expert_gemm(
    const unsigned short* __restrict__ Asrc, const unsigned short* __restrict__ Bt,
    const float* __restrict__ bias, const int* __restrict__ offsets,
    const int* __restrict__ list, const float* __restrict__ gates,
    unsigned short* __restrict__ hid, float* __restrict__ out,
    const float* __restrict__ w2src, unsigned short* __restrict__ w2dst) {
  constexpr int Krow = MODE ? DHID : DMODEL;   // row stride of A and B
  constexpr int Nout = MODE ? DMODEL : DHID;
  constexpr int NT = Krow / 32;                // fc1: 32, fc2: 128

  __shared__ alignas(16) unsigned short Al[3][128 * 32];
  __shared__ alignas(16) unsigned short Bl[3][128 * 32];

  const int gx = gridDim.x, gy = gridDim.y;
  const int lin = blockIdx.x + gx * (blockIdx.y + gy * blockIdx.z);

  if (MODE == 0 && lin >= 16384) {
    // ---- w2 transpose tile: [E][4096][1024] f32 -> [E][1024][4096] bf16 ----
    float (*sh)[65] = reinterpret_cast<float(*)[65]>(&Al[0][0]);  // 16.6 KB alias
    int t = lin - 16384;
    int e = t >> 10, rem = t & 1023;
    const int R = DHID, C = DMODEL;
    const float* in = w2src + (size_t)e * R * C;
    unsigned short* outp = w2dst + (size_t)e * R * C;
    int r0 = (rem >> 4) * 64;
    int c0 = (rem & 15) * 64;
    int tx = threadIdx.x & 15, ty = threadIdx.x >> 4;
#pragma unroll
    for (int p = 0; p < 4; ++p) {
      int row = ty + p * 16;
      float4 v = *(const float4*)&in[(size_t)(r0 + row) * C + c0 + tx * 4];
      sh[row][tx * 4 + 0] = v.x;
      sh[row][tx * 4 + 1] = v.y;
      sh[row][tx * 4 + 2] = v.z;
      sh[row][tx * 4 + 3] = v.w;
    }
    __syncthreads();
#pragma unroll
    for (int p = 0; p < 4; ++p) {
      int crow = ty + p * 16;
      ushort4 o;
      o.x = f2bf(sh[tx * 4 + 0][crow]);
      o.y = f2bf(sh[tx * 4 + 1][crow]);
      o.z = f2bf(sh[tx * 4 + 2][crow]);
      o.w = f2bf(sh[tx * 4 + 3][crow]);
      *(ushort4*)&outp[(size_t)(c0 + crow) * R + r0 + tx * 4] = o;
    }
    return;
  }

  const int e = lin & 7;                       // expert == XCD (lin % 8)
  int r = lin >> 3;

  int by, bx;
  if (MODE == 0) {
    int st = r >> 6;                           // supertile 0..31
    int inner = r & 63;
    int sm = st >> 2, sn = st & 3;
    if (sm & 1) sn = 3 - sn;                   // serpentine: A-super stays hot
    by = sm * 8 + (inner >> 3);                // 0..63
    bx = sn * 8 + (inner & 7);                 // 0..31
  } else {
    by = r & 63;
    bx = r >> 6;                               // 0..7
  }

  const int off = offsets[e];
  const int ne = offsets[e + 1] - off;
  const int m0 = by * 128;
  if (m0 >= ne) return;
  const int n0 = bx * 128;

  const int tid = threadIdx.x;
  const int lane = tid & 63;
  const int w = tid >> 6;
  const int wm = (w >> 1) * 64;
  const int wn = (w & 1) * 64;
  const int lr = lane & 15;
  const int kg = lane >> 4;
  const int chrd = (kg ^ ((lr >> 1) & 3)) * 8;  // swizzled ds_read chunk (ushorts)

  // per-thread staging sources (2 x 16B chunks each for A and B per K-tile)
  const unsigned short* srcA[2];
  const unsigned short* srcB[2];
#pragma unroll
  for (int i = 0; i < 2; ++i) {
    int q = tid + i * 256;           // chunk-linear in 128x32 tile (4 chunks/row)
    int rr = q >> 2, c = q & 3;
    int cs = c ^ ((rr >> 1) & 3);    // inverse-swizzled source chunk
    int p = off + imin(m0 + rr, ne - 1);
    if (MODE == 0) {
      int token = list[p] >> 1;
      srcA[i] = Asrc + (size_t)token * DMODEL + cs * 8;
    } else {
      srcA[i] = Asrc + (size_t)p * DHID + cs * 8;
    }
    srcB[i] = Bt + (size_t)e * Nout * Krow + (size_t)(n0 + rr) * Krow + cs * 8;
  }

  f32x4 acc[4][4] = {};

  auto stage = [&](int slot, int kt) {
#pragma unroll
    for (int i = 0; i < 2; ++i) {
      int q = tid + i * 256;
      gload_lds16(srcA[i] + kt * 32, &Al[slot][q * 8]);
      gload_lds16(srcB[i] + kt * 32, &Bl[slot][q * 8]);
    }
  };

  auto compute = [&](int slot) {
    bf16x8 af[4], bfr[4];
#pragma unroll
    for (int mf = 0; mf < 4; ++mf)
      af[mf] = *(const bf16x8*)&Al[slot][(wm + mf * 16 + lr) * 32 + chrd];
#pragma unroll
    for (int nf = 0; nf < 4; ++nf)
      bfr[nf] = *(const bf16x8*)&Bl[slot][(wn + nf * 16 + lr) * 32 + chrd];
    asm volatile("s_waitcnt lgkmcnt(0)" ::: "memory");
    __builtin_amdgcn_sched_barrier(0);
#pragma unroll
    for (int mf = 0; mf < 4; ++mf)
#pragma unroll
      for (int nf = 0; nf < 4; ++nf)
        acc[mf][nf] = __builtin_amdgcn_mfma_f32_16x16x32_bf16(af[mf], bfr[nf],
                                                              acc[mf][nf], 0, 0, 0);
  };

  // prologue: fill the 3-slot ring (12 loads/thread outstanding)
  stage(0, 0);
  stage(1, 1);
  stage(2, 2);

  int cur = 0;
  for (int t = 0; t < NT; ++t) {
    if (t < NT - 2) { VMW(8); }        // tile t retired; t+1,t+2 in flight
    else if (t == NT - 2) { VMW(4); }
    else { VMW(0); }
    __builtin_amdgcn_s_barrier();      // tile t fully in LDS for all waves
    __builtin_amdgcn_sched_barrier(0);
    compute(cur);
    asm volatile("s_waitcnt lgkmcnt(0)" ::: "memory");
    __builtin_amdgcn_sched_barrier(0);
    __builtin_amdgcn_s_barrier();      // all waves done reading slot cur
    if (t + 3 < NT) stage(cur, t + 3); // overwrite freed slot, 2 steps ahead
    cur = (cur == 2) ? 0 : cur + 1;
  }

  // epilogue: C frag (16x16): col = lane&15, row = (lane>>4)*4 + j
  if (MODE == 0) {
#pragma unroll
    for (int mf = 0; mf < 4; ++mf) {
#pragma unroll
      for (int j = 0; j < 4; ++j) {
        int rloc = wm + mf * 16 + kg * 4 + j;
        int row = m0 + rloc;
        if (row < ne) {
          size_t p = (size_t)(off + row);
#pragma unroll
          for (int nf = 0; nf < 4; ++nf) {
            int col = n0 + wn + nf * 16 + lr;
            float v = acc[mf][nf][j] + bias[(size_t)e * Nout + col];
            hid[p * DHID + col] = f2bf(fmaxf(v, 0.f));
          }
        }
      }
    }
  } else {
#pragma unroll
    for (int mf = 0; mf < 4; ++mf) {
#pragma unroll
      for (int j = 0; j < 4; ++j) {
        int rloc = wm + mf * 16 + kg * 4 + j;
        int row = m0 + rloc;
        if (row < ne) {
          int lv = list[off + row];
          int token = lv >> 1;
          float g = gates[lv];
#pragma unroll
          for (int nf = 0; nf < 4; ++nf) {
            int col = n0 + wn + nf * 16 + lr;
            float v = (acc[mf][nf][j] + bias[(size_t)e * Nout + col]) * g;
            atomicAdd(&out[(size_t)token * DMODEL + col], v);
          }
        }
      }
    }
  }
}

extern "C" void kernel_launch(void* const* d_in, const int* in_sizes, int n_in,
                              void* d_out, int out_size, void* d_ws, size_t ws_size,
                              hipStream_t stream) {
  const float* x = (const float*)d_in[0];
  const float* noise = (const float*)d_in[1];
  const float* Wg_w = (const float*)d_in[2];
  const float* Wg_b = (const float*)d_in[3];
  const float* Wn_w = (const float*)d_in[4];
  const float* Wn_b = (const float*)d_in[5];
  const float* w1 = (const float*)d_in[6];
  const float* b1 = (const float*)d_in[7];
  const float* w2 = (const float*)d_in[8];
  const float* b2 = (const float*)d_in[9];
  float* out = (float*)d_out;

  char* ws = (char*)d_ws;
  unsigned short* xb = (unsigned short*)(ws + OFF_XB);
  unsigned short* w1t = (unsigned short*)(ws + OFF_W1T);
  unsigned short* w2t = (unsigned short*)(ws + OFF_W2T);
  unsigned short* hid = (unsigned short*)(ws + OFF_HID);
  int* topk_idx = (int*)(ws + OFF_IDX);
  float* topk_gate = (float*)(ws + OFF_GATE);
  int* list = (int*)(ws + OFF_LIST);
  int* counts = (int*)(ws + OFF_CNT);
  int* offsets = (int*)(ws + OFF_OFFS);
  int* cursor = (int*)(ws + OFF_CUR);

  hipMemsetAsync(out, 0, (size_t)NTOK * DMODEL * sizeof(float), stream);
  hipMemsetAsync(counts, 0, NEXP * sizeof(int), stream);

  // prep: w1 transpose (8192 blocks) + gating (2048 blocks)
  prep_kernel<<<10240, 256, 0, stream>>>(w1, w1t, x, noise, Wg_w, Wg_b,
                                         Wn_w, Wn_b, xb, topk_idx, topk_gate,
                                         counts);
  scan_kernel<<<1, 64, 0, stream>>>(counts, offsets, cursor);
  scatter_kernel<<<NTOK / 256, 256, 0, stream>>>(topk_idx, cursor, list);

  // fc1 GEMM (16384 blocks) + w2 transpose (8192 blocks) in one heterogeneous
  // grid: transpose blocks backfill as GEMM blocks retire, overlapping the w2
  // HBM read with fc1's staging-bound compute.
  expert_gemm<0><<<dim3(24576, 1, 1), 256, 0, stream>>>(
      xb, w1t, b1, offsets, list, topk_gate, hid, nullptr, w2, w2t);
  // fc2: out += gate * (hid[ne x 4096] * B[4096 x 1024])
  expert_gemm<1><<<dim3(8, 64, NEXP), 256, 0, stream>>>(
      hid, w2t, b2, offsets, list, topk_gate, nullptr, out, nullptr, nullptr);
}